// Round 14
// baseline (85.052 us; speedup 1.0000x reference)
//
#include <hip/hip_runtime.h>
#include <stdint.h>
#include <math.h>
#include <array>
#include <utility>

#ifndef M_PI
#define M_PI 3.14159265358979323846
#endif

#define NNODES 2048
#define L2DIM  16
#define CIN    384
#define CHID   256

typedef __attribute__((ext_vector_type(8))) short short8;
typedef __attribute__((ext_vector_type(4))) float f32x4;
typedef unsigned short u16;
typedef unsigned int   u32;

#define LOF(i) ((i) < 1 ? 0 : ((i) < 4 ? 1 : ((i) < 9 ? 2 : 3)))

static __device__ __forceinline__ u16 f2bf(float f) {
  u32 u = __builtin_bit_cast(u32, f);
  u = u + 0x7FFFu + ((u >> 16) & 1u);   // RNE
  return (u16)(u >> 16);
}
static __device__ __forceinline__ float bf2f(u16 b) {
  u32 u = ((u32)b) << 16;
  return __builtin_bit_cast(float, u);
}

// ===========================================================================
// COMPILE-TIME Gaunt coefficients (validated round 3: absmax 0.0625).
// ===========================================================================
constexpr double CPI = 3.14159265358979323846;

constexpr double csqrt(double x) {
  if (x <= 0.0) return 0.0;
  double y = x > 1.0 ? x : 1.0;
  for (int i = 0; i < 48; ++i) y = 0.5 * (y + x / y);
  return y;
}
constexpr double ccos(double x) {
  double r = x;
  while (r > CPI)  r -= 2.0 * CPI;
  while (r < -CPI) r += 2.0 * CPI;
  double r2 = r * r, term = 1.0, sum = 1.0;
  for (int i = 1; i <= 26; ++i) { term *= -r2 / ((2.0 * i - 1.0) * (2.0 * i)); sum += term; }
  return sum;
}
constexpr int iabs_c(int x) { return x < 0 ? -x : x; }

struct GLQ { double x[16]; double w[16]; };
constexpr GLQ build_gl() {
  GLQ g{};
  const int n = 16;
  for (int i = 0; i < n; ++i) {
    double x = ccos(CPI * (i + 0.75) / (n + 0.5));
    double p1 = 0.0, dp = 1.0;
    for (int it = 0; it < 40; ++it) {
      double p0 = 1.0; p1 = x;
      for (int k = 2; k <= n; ++k) { double p2 = ((2.0*k-1.0)*x*p1 - (k-1.0)*p0)/k; p0 = p1; p1 = p2; }
      dp = n * (x*p1 - p0) / (x*x - 1.0);
      x -= p1 / dp;
    }
    { double p0 = 1.0; p1 = x;
      for (int k = 2; k <= n; ++k) { double p2 = ((2.0*k-1.0)*x*p1 - (k-1.0)*p0)/k; p0 = p1; p1 = p2; }
      dp = n * (x*p1 - p0) / (x*x - 1.0); }
    g.x[i] = x;
    g.w[i] = 2.0 / ((1.0 - x*x) * dp * dp);
  }
  return g;
}
constexpr GLQ QG = build_gl();

struct PTab { double v[4][4][16]; };
constexpr PTab build_pbar() {
  PTab T{};
  for (int t = 0; t < 16; ++t) {
    double ct = QG.x[t];
    double st = csqrt(1.0 - ct * ct);
    double P[4][4] = {};
    P[0][0] = csqrt(1.0 / (4.0 * CPI));
    for (int m = 1; m <= 3; ++m)
      P[m][m] = csqrt((2.0*m + 1.0) / (2.0*m)) * st * P[m-1][m-1];
    for (int m = 0; m <= 3; ++m) {
      if (m + 1 <= 3) P[m+1][m] = csqrt(2.0*m + 3.0) * ct * P[m][m];
      for (int l = m + 2; l <= 3; ++l) {
        double aa = csqrt((4.0*(double)l*l - 1.0) / ((double)l*l - (double)m*m));
        double bb = csqrt(((double)(l-1)*(l-1) - (double)m*m) / (4.0*(double)(l-1)*(l-1) - 1.0));
        P[l][m] = aa * (ct * P[l-1][m] - bb * P[l-2][m]);
      }
    }
    for (int l = 0; l < 4; ++l)
      for (int m = 0; m <= l; ++m) T.v[l][m][t] = P[l][m];
  }
  return T;
}
constexpr PTab PT = build_pbar();

constexpr double phi_int(int m1, int m2, int m3) {
  const double SQ2 = 1.41421356237309504880;
  int neg = (m1 < 0) + (m2 < 0) + (m3 < 0);
  if (neg & 1) return 0.0;
  int a = iabs_c(m1), b = iabs_c(m2), c = iabs_c(m3);
  int nz = (a > 0) + (b > 0) + (c > 0);
  if (nz == 0) return 2.0 * CPI;
  if (nz == 1) return 0.0;
  if (nz == 2) {
    int p = 0, q = 0;
    if (a == 0) { p = b; q = c; } else if (b == 0) { p = a; q = c; } else { p = a; q = b; }
    return (p == q) ? 2.0 * CPI : 0.0;
  }
  if (neg == 0) {
    double v = 0.0;
    if (iabs_c(a - b) == c && a != b) v += 1.0;
    if (a + b == c) v += 1.0;
    return SQ2 * CPI * v;
  }
  int p = 0, q = 0, r = 0;
  if (m1 > 0)      { p = a; q = b; r = c; }
  else if (m2 > 0) { p = b; q = a; r = c; }
  else             { p = c; q = a; r = b; }
  double v = 0.0;
  if (q != r && p == iabs_c(q - r)) v += 1.0;
  if (p == q + r) v -= 1.0;
  return SQ2 * CPI * v;
}

constexpr bool path_ok(int l1, int l2, int l3) {
  int lo = l1 > l2 ? l1 - l2 : l2 - l1;
  return l3 >= lo && l3 <= l1 + l2 && (((l1 + l2 + l3) & 1) == 0);
}
constexpr bool term_ok(int m1, int m2, int m3) {
  int aa = iabs_c(m1), bb = iabs_c(m2), cc = iabs_c(m3);
  int neg = (m1 < 0) + (m2 < 0) + (m3 < 0);
  if (neg & 1) return false;
  return (aa + bb == cc) || (bb + cc == aa) || (cc + aa == bb);
}
constexpr int count_paths() {
  int n = 0;
  for (int l1 = 0; l1 < 4; ++l1) for (int l2 = 0; l2 < 4; ++l2) for (int l3 = 0; l3 < 4; ++l3)
    if (path_ok(l1, l2, l3)) ++n;
  return n;
}
constexpr int NPATHS = count_paths();   // 23
constexpr int NTMAX  = 512;

constexpr double term_g(int l1, int m1, int l2, int m2, int l3, int m3) {
  double ph = phi_int(m1, m2, m3);
  if (ph == 0.0) return 0.0;
  int a = iabs_c(m1), b = iabs_c(m2), c = iabs_c(m3);
  double s = 0.0;
  for (int t = 0; t < 16; ++t)
    s += QG.w[t] * PT.v[l1][a][t] * PT.v[l2][b][t] * PT.v[l3][c][t];
  double g = ph * s;
  double fan = (l3 == 0) ? 4.0 : (l3 == 1 ? 6.0 : (l3 == 2 ? 7.0 : 6.0));
  return g * csqrt((2.0 * (double)l3 + 1.0) / fan);
}

struct TermG { float g; unsigned char i, j, k, p; };
struct PathT { unsigned char l1, l2, l3; };
struct TGAll { TermG t[NTMAX]; int n; };
constexpr TGAll build_all() {
  TGAll r{};
  r.n = 0;
  int p = 0;
  for (int l1 = 0; l1 < 4; ++l1) for (int l2 = 0; l2 < 4; ++l2) for (int l3 = 0; l3 < 4; ++l3) {
    if (!path_ok(l1, l2, l3)) continue;
    for (int m1 = -l1; m1 <= l1; ++m1) for (int m2 = -l2; m2 <= l2; ++m2) for (int m3 = -l3; m3 <= l3; ++m3) {
      if (!term_ok(m1, m2, m3)) continue;
      double g = term_g(l1, m1, l2, m2, l3, m3);
      if (g > 1e-10 || g < -1e-10) {
        r.t[r.n].g = (float)g;
        r.t[r.n].i = (unsigned char)(l1 * l1 + l1 + m1);
        r.t[r.n].j = (unsigned char)(l2 * l2 + l2 + m2);
        r.t[r.n].k = (unsigned char)(l3 * l3 + l3 + m3);
        r.t[r.n].p = (unsigned char)p;
        ++r.n;
      }
    }
    ++p;
  }
  return r;
}
constexpr TGAll TGA = build_all();
constexpr int NNZ = TGA.n;

constexpr std::array<PathT, NPATHS> build_paths() {
  std::array<PathT, NPATHS> a{};
  int n = 0;
  for (int l1 = 0; l1 < 4; ++l1) for (int l2 = 0; l2 < 4; ++l2) for (int l3 = 0; l3 < 4; ++l3)
    if (path_ok(l1, l2, l3)) a[n++] = PathT{(unsigned char)l1, (unsigned char)l2, (unsigned char)l3};
  return a;
}
constexpr auto PATHS_ARR = build_paths();

template <size_t... Is>
__device__ __forceinline__ void gaunt_terms(std::index_sequence<Is...>,
    float* __restrict__ t, const float* __restrict__ h,
    const float* __restrict__ wgv) {
  ((t[TGA.t[Is].k] = fmaf(TGA.t[Is].g * wgv[TGA.t[Is].p],
                          h[TGA.t[Is].i] * h[TGA.t[Is].j],
                          t[TGA.t[Is].k])), ...);
}
// two-channel wgv load via float2 (c even)
template <size_t... Ps>
__device__ __forceinline__ void load_wgv2(std::index_sequence<Ps...>,
    float* __restrict__ w0, float* __restrict__ w1,
    const float* __restrict__ wg, int c) {
  float2 tmp;
  (((tmp = *reinterpret_cast<const float2*>(
        &wg[(size_t)(((int)PATHS_ARR[Ps].l1 * 4 + (int)PATHS_ARR[Ps].l2) * 4
                     + (int)PATHS_ARR[Ps].l3) * CHID + c]),
     w0[Ps] = tmp.x, w1[Ps] = tmp.y)), ...);
}

// ---------------------------------------------------------------------------
// prep_kernel: blocks [0,2048) layernorm; blocks [2048,3200) weight transpose.
// ---------------------------------------------------------------------------
__global__ __launch_bounds__(256) void prep_kernel(
    const float* __restrict__ x, const float* __restrict__ nw,
    const float* __restrict__ nb, u16* __restrict__ xnb,
    const float* __restrict__ w1, const float* __restrict__ w2,
    u16* __restrict__ w1t, u16* __restrict__ w2t) {
  int bid = blockIdx.x, tid = threadIdx.x;
  if (bid >= NNODES) {
    __shared__ float tile[32][33];
    int b2 = bid - NNODES;
    int z = b2 / 144, rem = b2 % 144;
    int by = rem / 12, bx = rem % 12;
    int R = z < 4 ? 384 : 256, C = z < 4 ? 256 : 384;
    int r0 = by * 32, c0 = bx * 32;
    if (r0 >= R || c0 >= C) return;
    const float* s = (z < 4 ? w1 : w2) + (size_t)(z & 3) * R * C;
    u16* d = (z < 4 ? w1t : w2t) + (size_t)(z & 3) * R * C;
    int tx = tid & 31, ty = tid >> 5;
    for (int rr = ty; rr < 32; rr += 8)
      tile[rr][tx] = s[(size_t)(r0 + rr) * C + (c0 + tx)];
    __syncthreads();
    for (int cc = ty; cc < 32; cc += 8)
      d[(size_t)(c0 + cc) * R + (r0 + tx)] = f2bf(tile[tx][cc]);
    return;
  }
  int n = bid;
  const float* xr = x + (size_t)n * (L2DIM * CIN);
  __shared__ float2 red[4];
  float4 v[6];
  float ssq = 0.f, m0p = 0.f;
#pragma unroll
  for (int q = 0; q < 6; ++q) {
    v[q] = reinterpret_cast<const float4*>(xr)[tid * 6 + q];
    ssq += v[q].x*v[q].x + v[q].y*v[q].y + v[q].z*v[q].z + v[q].w*v[q].w;
  }
  if (tid < 16) {
#pragma unroll
    for (int q = 0; q < 6; ++q) m0p += v[q].x + v[q].y + v[q].z + v[q].w;
  }
  float a = m0p, b = ssq;
#pragma unroll
  for (int off = 32; off > 0; off >>= 1) { a += __shfl_down(a, off, 64); b += __shfl_down(b, off, 64); }
  int lane = tid & 63, wid = tid >> 6;
  if (lane == 0) red[wid] = make_float2(a, b);
  __syncthreads();
  float sum0 = red[0].x + red[1].x + red[2].x + red[3].x;
  float ssqt = red[0].y + red[1].y + red[2].y + red[3].y;
  float mean0 = sum0 * (1.0f / CIN);
  float ss = ssqt - (float)CIN * mean0 * mean0;
  float rstd = rsqrtf(ss * (1.0f / (L2DIM * CIN)) + 1e-5f);

  int lm = tid >> 4;
  int l = LOF(lm);
  bool row0 = (lm == 0);
  int cbase = (tid & 15) * 24;
  u16* orow = xnb + (size_t)n * (L2DIM * CIN) + (size_t)tid * 24;
#pragma unroll
  for (int q = 0; q < 6; ++q) {
    int c = cbase + q * 4;
    float4 w4 = *reinterpret_cast<const float4*>(&nw[l * CIN + c]);
    float4 b4 = row0 ? *reinterpret_cast<const float4*>(&nb[c]) : make_float4(0,0,0,0);
    float sub = row0 ? mean0 : 0.f;
    float o0 = (v[q].x - sub) * rstd * w4.x + b4.x;
    float o1 = (v[q].y - sub) * rstd * w4.y + b4.y;
    float o2 = (v[q].z - sub) * rstd * w4.z + b4.z;
    float o3 = (v[q].w - sub) * rstd * w4.w + b4.w;
    ushort4 pk;
    pk.x = f2bf(o0); pk.y = f2bf(o1); pk.z = f2bf(o2); pk.w = f2bf(o3);
    *reinterpret_cast<ushort4*>(&orow[q * 4]) = pk;
  }
}

// ---------------------------------------------------------------------------
// Per-degree GEMM, swapped operands (D[chan][node-lm]), BM=128 x BN=128,
// 4 waves (2x2), wave tile 64x64, acc[4][4], 2-phase pipelined dbuf LDS.
// r14: XCD swizzle REMOVED (r13 A/B: costs ~3 us when working set L3-fits,
// per guide m160); flat exact grid KEPT (no ghost blocks). Resid prefetched
// in K-loop with normal cached float4 loads (r11 win, +4.5 us).
// ---------------------------------------------------------------------------
template <int KD, int NDC, bool SECOND>
__global__ __launch_bounds__(256, 2) void so3_gemm_kernel(
    const u16* __restrict__ X, const u16* __restrict__ WT,
    const float* __restrict__ bias, const float* __restrict__ resid,
    u16* __restrict__ outb, float* __restrict__ outf) {
  constexpr int KT = KD / 64;               // K-tiles (6 or 4)
  // ---- flat tile index, natural order (256 tiles) ----
  int t = blockIdx.x;
  int l, tbase;
  if (t < 16)       { l = 0; tbase = 0; }
  else if (t < 64)  { l = 1; tbase = 16; }
  else if (t < 144) { l = 2; tbase = 64; }
  else              { l = 3; tbase = 144; }
  int bx = t - tbase;
  int twol1 = 2 * l + 1;
  int by = blockIdx.y;
  int tid = threadIdx.x, lane = tid & 63, wid = tid >> 6;
  int wm = wid >> 1, wn = wid & 1;            // wm: chan half, wn: nodelm half

  __shared__ u16 Wsm[2][128 * 64];            // 2 x 16 KB (chan rows)
  __shared__ u16 Xsm[2][128 * 64];            // 2 x 16 KB (node-lm rows)

  const u16* wsrc[4];
  const u16* xsrc[4];
#pragma unroll
  for (int i = 0; i < 4; ++i) {
    int r = i * 32 + (tid >> 3);
    wsrc[i] = WT + (size_t)(l * NDC + by * 128 + r) * KD + ((tid & 7) ^ (r & 7)) * 8;
    int Rg = bx * 128 + r;
    int node = Rg / twol1;
    int lm = l * l + (Rg - node * twol1);
    xsrc[i] = X + (size_t)(node * L2DIM + lm) * KD + ((tid & 7) ^ (r & 7)) * 8;
  }

  auto stage = [&](int buf, int kt) {
#pragma unroll
    for (int i = 0; i < 4; ++i)
      __builtin_amdgcn_global_load_lds(
          (const __attribute__((address_space(1))) void*)(wsrc[i] + kt * 64),
          (__attribute__((address_space(3))) void*)(&Wsm[buf][i * 2048 + wid * 512]),
          16, 0, 0);
#pragma unroll
    for (int i = 0; i < 4; ++i)
      __builtin_amdgcn_global_load_lds(
          (const __attribute__((address_space(1))) void*)(xsrc[i] + kt * 64),
          (__attribute__((address_space(3))) void*)(&Xsm[buf][i * 2048 + wid * 512]),
          16, 0, 0);
  };

  f32x4 acc[4][4];
#pragma unroll
  for (int i = 0; i < 4; ++i)
#pragma unroll
    for (int j = 0; j < 4; ++j) acc[i][j] = (f32x4){0.f, 0.f, 0.f, 0.f};

  float4 rv[4][4];   // resid prefetch (SECOND only): rv[mf][nf]

  stage(0, 0);
  __syncthreads();
#pragma unroll
  for (int kt = 0; kt < KT; ++kt) {
    int cur = kt & 1;
    if (kt + 1 < KT) stage(cur ^ 1, kt + 1);
    if constexpr (SECOND) {
      // prefetch one mf-row of resid fragments per K-tile (KT == 4);
      // normal cached loads: partial-line reads combine in L2.
      if (kt < 4) {
        int mf = kt;
        int chan0 = by * 128 + wm * 64 + mf * 16 + (lane >> 4) * 4;
#pragma unroll
        for (int nf = 0; nf < 4; ++nf) {
          int nodelm_g = bx * 128 + wn * 64 + nf * 16 + (lane & 15);
          int node = nodelm_g / twol1;
          int lm = l * l + (nodelm_g - node * twol1);
          rv[mf][nf] = *reinterpret_cast<const float4*>(
              &resid[(size_t)(node * L2DIM + lm) * NDC + chan0]);
        }
      }
    }
#pragma unroll
    for (int ks = 0; ks < 2; ++ks) {
      short8 wf[4], xf[4];
#pragma unroll
      for (int mf = 0; mf < 4; ++mf) {
        int row = wm * 64 + mf * 16 + (lane & 15);
        int slot = (ks * 4 + (lane >> 4)) ^ (row & 7);
        wf[mf] = *reinterpret_cast<const short8*>(&Wsm[cur][row * 64 + slot * 8]);
      }
#pragma unroll
      for (int nf = 0; nf < 4; ++nf) {
        int row = wn * 64 + nf * 16 + (lane & 15);
        int slot = (ks * 4 + (lane >> 4)) ^ (row & 7);
        xf[nf] = *reinterpret_cast<const short8*>(&Xsm[cur][row * 64 + slot * 8]);
      }
#pragma unroll
      for (int mf = 0; mf < 4; ++mf)
#pragma unroll
        for (int nf = 0; nf < 4; ++nf)
          acc[mf][nf] = __builtin_amdgcn_mfma_f32_16x16x32_bf16(wf[mf], xf[nf], acc[mf][nf], 0, 0, 0);
    }
    __syncthreads();
  }

  // ---- epilogue: lane holds 4 consecutive chans of one node-lm row ----
#pragma unroll
  for (int mf = 0; mf < 4; ++mf) {
#pragma unroll
    for (int nf = 0; nf < 4; ++nf) {
      int nodelm_g = bx * 128 + wn * 64 + nf * 16 + (lane & 15);
      int node = nodelm_g / twol1;
      int lm = l * l + (nodelm_g - node * twol1);
      int chan0 = by * 128 + wm * 64 + mf * 16 + (lane >> 4) * 4;
      size_t base = (size_t)(node * L2DIM + lm) * NDC + chan0;
      float4 v = make_float4(acc[mf][nf][0], acc[mf][nf][1],
                             acc[mf][nf][2], acc[mf][nf][3]);
      if (l == 0) {
        float4 b4 = *reinterpret_cast<const float4*>(&bias[chan0]);
        v.x += b4.x; v.y += b4.y; v.z += b4.z; v.w += b4.w;
      }
      if (!SECOND) {
        ushort4 pk;
        pk.x = f2bf(v.x); pk.y = f2bf(v.y); pk.z = f2bf(v.z); pk.w = f2bf(v.w);
        *reinterpret_cast<ushort4*>(&outb[base]) = pk;
      } else {
        v.x += rv[mf][nf].x; v.y += rv[mf][nf].y;
        v.z += rv[mf][nf].z; v.w += rv[mf][nf].w;
        *reinterpret_cast<float4*>(&outf[base]) = v;
      }
    }
  }
}

// ---------------------------------------------------------------------------
// Depthwise Gaunt TP, 2 channels/thread (u32 packed I/O), block covers 2 nodes.
// ---------------------------------------------------------------------------
__global__ __launch_bounds__(256) void gaunt_kernel(
    const u16* __restrict__ hb, const float* __restrict__ wg,
    u16* __restrict__ tb) {
  int tid = threadIdx.x;
  int n = blockIdx.x * 2 + (tid >> 7);
  int c = (tid & 127) * 2;
  const u16* hr = hb + (size_t)n * (L2DIM * CHID) + c;
  float h0[16], h1[16];
#pragma unroll
  for (int i = 0; i < 16; ++i) {
    u32 w = *reinterpret_cast<const u32*>(&hr[i * CHID]);
    h0[i] = bf2f((u16)(w & 0xffffu));
    h1[i] = bf2f((u16)(w >> 16));
  }

  float w0[NPATHS], w1[NPATHS];
  load_wgv2(std::make_index_sequence<NPATHS>{}, w0, w1, wg, c);

  float t0[16], t1[16];
#pragma unroll
  for (int k = 0; k < 16; ++k) { t0[k] = 0.f; t1[k] = 0.f; }

  gaunt_terms(std::make_index_sequence<NNZ>{}, t0, h0, w0);
  gaunt_terms(std::make_index_sequence<NNZ>{}, t1, h1, w1);

  u16* tr = tb + (size_t)n * (L2DIM * CHID) + c;
#pragma unroll
  for (int k = 0; k < 16; ++k) {
    u32 o = (u32)f2bf(t0[k]) | ((u32)f2bf(t1[k]) << 16);
    *reinterpret_cast<u32*>(&tr[k * CHID]) = o;
  }
}

// ---------------------------------------------------------------------------
extern "C" void kernel_launch(void* const* d_in, const int* in_sizes, int n_in,
                              void* d_out, int out_size, void* d_ws, size_t ws_size,
                              hipStream_t stream) {
  const float* inputs = (const float*)d_in[0];
  // d_in[1] = batch (unused: drop paths disabled)
  const float* norm_w = (const float*)d_in[2];
  const float* norm_b = (const float*)d_in[3];
  const float* w1     = (const float*)d_in[4];
  const float* b1     = (const float*)d_in[5];
  const float* wga    = (const float*)d_in[6];
  const float* w2     = (const float*)d_in[7];
  const float* b2     = (const float*)d_in[8];
  float* out = (float*)d_out;

  uint8_t* ws = (uint8_t*)d_ws;
  u16*   w1t = (u16*)(ws + 16384);          // [4][256][384] bf16, 768 KB
  u16*   w2t = (u16*)(ws + 802816);         // [4][384][256] bf16, 768 KB
  u16*   xnb = (u16*)(ws + 1589248);        // [2048][16][384] bf16, 24 MB
  u16*   tb  = xnb;                         // reuse after GEMM1 consumed xnb
  u16*   hb  = (u16*)(ws + 26755072);       // [2048][16][256] bf16, 16 MB

  prep_kernel<<<NNODES + 1152, 256, 0, stream>>>(
      inputs, norm_w, norm_b, xnb, w1, w2, w1t, w2t);
  // gemm1: X=xnb (K=384), W=w1t (256 chans -> by 0..1) -> hb bf16
  so3_gemm_kernel<CIN, CHID, false><<<dim3(256, 2), 256, 0, stream>>>(
      xnb, w1t, b1, nullptr, hb, nullptr);
  gaunt_kernel<<<NNODES / 2, 256, 0, stream>>>(hb, wga, tb);
  // gemm2: X=tb (K=256), W=w2t (384 chans -> by 0..2) -> out f32 (+resid)
  so3_gemm_kernel<CHID, CIN, true><<<dim3(256, 3), 256, 0, stream>>>(
      tb, w2t, b2, inputs, nullptr, out);
}

// Round 15
// 79.647 us; speedup vs baseline: 1.0679x; 1.0679x over previous
//
#include <hip/hip_runtime.h>
#include <stdint.h>
#include <math.h>
#include <array>
#include <utility>

#ifndef M_PI
#define M_PI 3.14159265358979323846
#endif

#define NNODES 2048
#define L2DIM  16
#define CIN    384
#define CHID   256

typedef __attribute__((ext_vector_type(8))) short short8;
typedef __attribute__((ext_vector_type(4))) float f32x4;
typedef unsigned short u16;
typedef unsigned int   u32;

#define LOF(i) ((i) < 1 ? 0 : ((i) < 4 ? 1 : ((i) < 9 ? 2 : 3)))

static __device__ __forceinline__ u16 f2bf(float f) {
  u32 u = __builtin_bit_cast(u32, f);
  u = u + 0x7FFFu + ((u >> 16) & 1u);   // RNE
  return (u16)(u >> 16);
}
static __device__ __forceinline__ float bf2f(u16 b) {
  u32 u = ((u32)b) << 16;
  return __builtin_bit_cast(float, u);
}

// ===========================================================================
// COMPILE-TIME Gaunt coefficients (validated round 3: absmax 0.0625).
// ===========================================================================
constexpr double CPI = 3.14159265358979323846;

constexpr double csqrt(double x) {
  if (x <= 0.0) return 0.0;
  double y = x > 1.0 ? x : 1.0;
  for (int i = 0; i < 48; ++i) y = 0.5 * (y + x / y);
  return y;
}
constexpr double ccos(double x) {
  double r = x;
  while (r > CPI)  r -= 2.0 * CPI;
  while (r < -CPI) r += 2.0 * CPI;
  double r2 = r * r, term = 1.0, sum = 1.0;
  for (int i = 1; i <= 26; ++i) { term *= -r2 / ((2.0 * i - 1.0) * (2.0 * i)); sum += term; }
  return sum;
}
constexpr int iabs_c(int x) { return x < 0 ? -x : x; }

struct GLQ { double x[16]; double w[16]; };
constexpr GLQ build_gl() {
  GLQ g{};
  const int n = 16;
  for (int i = 0; i < n; ++i) {
    double x = ccos(CPI * (i + 0.75) / (n + 0.5));
    double p1 = 0.0, dp = 1.0;
    for (int it = 0; it < 40; ++it) {
      double p0 = 1.0; p1 = x;
      for (int k = 2; k <= n; ++k) { double p2 = ((2.0*k-1.0)*x*p1 - (k-1.0)*p0)/k; p0 = p1; p1 = p2; }
      dp = n * (x*p1 - p0) / (x*x - 1.0);
      x -= p1 / dp;
    }
    { double p0 = 1.0; p1 = x;
      for (int k = 2; k <= n; ++k) { double p2 = ((2.0*k-1.0)*x*p1 - (k-1.0)*p0)/k; p0 = p1; p1 = p2; }
      dp = n * (x*p1 - p0) / (x*x - 1.0); }
    g.x[i] = x;
    g.w[i] = 2.0 / ((1.0 - x*x) * dp * dp);
  }
  return g;
}
constexpr GLQ QG = build_gl();

struct PTab { double v[4][4][16]; };
constexpr PTab build_pbar() {
  PTab T{};
  for (int t = 0; t < 16; ++t) {
    double ct = QG.x[t];
    double st = csqrt(1.0 - ct * ct);
    double P[4][4] = {};
    P[0][0] = csqrt(1.0 / (4.0 * CPI));
    for (int m = 1; m <= 3; ++m)
      P[m][m] = csqrt((2.0*m + 1.0) / (2.0*m)) * st * P[m-1][m-1];
    for (int m = 0; m <= 3; ++m) {
      if (m + 1 <= 3) P[m+1][m] = csqrt(2.0*m + 3.0) * ct * P[m][m];
      for (int l = m + 2; l <= 3; ++l) {
        double aa = csqrt((4.0*(double)l*l - 1.0) / ((double)l*l - (double)m*m));
        double bb = csqrt(((double)(l-1)*(l-1) - (double)m*m) / (4.0*(double)(l-1)*(l-1) - 1.0));
        P[l][m] = aa * (ct * P[l-1][m] - bb * P[l-2][m]);
      }
    }
    for (int l = 0; l < 4; ++l)
      for (int m = 0; m <= l; ++m) T.v[l][m][t] = P[l][m];
  }
  return T;
}
constexpr PTab PT = build_pbar();

constexpr double phi_int(int m1, int m2, int m3) {
  const double SQ2 = 1.41421356237309504880;
  int neg = (m1 < 0) + (m2 < 0) + (m3 < 0);
  if (neg & 1) return 0.0;
  int a = iabs_c(m1), b = iabs_c(m2), c = iabs_c(m3);
  int nz = (a > 0) + (b > 0) + (c > 0);
  if (nz == 0) return 2.0 * CPI;
  if (nz == 1) return 0.0;
  if (nz == 2) {
    int p = 0, q = 0;
    if (a == 0) { p = b; q = c; } else if (b == 0) { p = a; q = c; } else { p = a; q = b; }
    return (p == q) ? 2.0 * CPI : 0.0;
  }
  if (neg == 0) {
    double v = 0.0;
    if (iabs_c(a - b) == c && a != b) v += 1.0;
    if (a + b == c) v += 1.0;
    return SQ2 * CPI * v;
  }
  int p = 0, q = 0, r = 0;
  if (m1 > 0)      { p = a; q = b; r = c; }
  else if (m2 > 0) { p = b; q = a; r = c; }
  else             { p = c; q = a; r = b; }
  double v = 0.0;
  if (q != r && p == iabs_c(q - r)) v += 1.0;
  if (p == q + r) v -= 1.0;
  return SQ2 * CPI * v;
}

constexpr bool path_ok(int l1, int l2, int l3) {
  int lo = l1 > l2 ? l1 - l2 : l2 - l1;
  return l3 >= lo && l3 <= l1 + l2 && (((l1 + l2 + l3) & 1) == 0);
}
constexpr bool term_ok(int m1, int m2, int m3) {
  int aa = iabs_c(m1), bb = iabs_c(m2), cc = iabs_c(m3);
  int neg = (m1 < 0) + (m2 < 0) + (m3 < 0);
  if (neg & 1) return false;
  return (aa + bb == cc) || (bb + cc == aa) || (cc + aa == bb);
}
constexpr int count_paths() {
  int n = 0;
  for (int l1 = 0; l1 < 4; ++l1) for (int l2 = 0; l2 < 4; ++l2) for (int l3 = 0; l3 < 4; ++l3)
    if (path_ok(l1, l2, l3)) ++n;
  return n;
}
constexpr int NPATHS = count_paths();   // 23
constexpr int NTMAX  = 512;

constexpr double term_g(int l1, int m1, int l2, int m2, int l3, int m3) {
  double ph = phi_int(m1, m2, m3);
  if (ph == 0.0) return 0.0;
  int a = iabs_c(m1), b = iabs_c(m2), c = iabs_c(m3);
  double s = 0.0;
  for (int t = 0; t < 16; ++t)
    s += QG.w[t] * PT.v[l1][a][t] * PT.v[l2][b][t] * PT.v[l3][c][t];
  double g = ph * s;
  double fan = (l3 == 0) ? 4.0 : (l3 == 1 ? 6.0 : (l3 == 2 ? 7.0 : 6.0));
  return g * csqrt((2.0 * (double)l3 + 1.0) / fan);
}

struct TermG { float g; unsigned char i, j, k, p; };
struct PathT { unsigned char l1, l2, l3; };
struct TGAll { TermG t[NTMAX]; int n; };
constexpr TGAll build_all() {
  TGAll r{};
  r.n = 0;
  int p = 0;
  for (int l1 = 0; l1 < 4; ++l1) for (int l2 = 0; l2 < 4; ++l2) for (int l3 = 0; l3 < 4; ++l3) {
    if (!path_ok(l1, l2, l3)) continue;
    for (int m1 = -l1; m1 <= l1; ++m1) for (int m2 = -l2; m2 <= l2; ++m2) for (int m3 = -l3; m3 <= l3; ++m3) {
      if (!term_ok(m1, m2, m3)) continue;
      double g = term_g(l1, m1, l2, m2, l3, m3);
      if (g > 1e-10 || g < -1e-10) {
        r.t[r.n].g = (float)g;
        r.t[r.n].i = (unsigned char)(l1 * l1 + l1 + m1);
        r.t[r.n].j = (unsigned char)(l2 * l2 + l2 + m2);
        r.t[r.n].k = (unsigned char)(l3 * l3 + l3 + m3);
        r.t[r.n].p = (unsigned char)p;
        ++r.n;
      }
    }
    ++p;
  }
  return r;
}
constexpr TGAll TGA = build_all();
constexpr int NNZ = TGA.n;

constexpr std::array<PathT, NPATHS> build_paths() {
  std::array<PathT, NPATHS> a{};
  int n = 0;
  for (int l1 = 0; l1 < 4; ++l1) for (int l2 = 0; l2 < 4; ++l2) for (int l3 = 0; l3 < 4; ++l3)
    if (path_ok(l1, l2, l3)) a[n++] = PathT{(unsigned char)l1, (unsigned char)l2, (unsigned char)l3};
  return a;
}
constexpr auto PATHS_ARR = build_paths();

template <size_t... Is>
__device__ __forceinline__ void gaunt_terms(std::index_sequence<Is...>,
    float* __restrict__ t, const float* __restrict__ h,
    const float* __restrict__ wgv) {
  ((t[TGA.t[Is].k] = fmaf(TGA.t[Is].g * wgv[TGA.t[Is].p],
                          h[TGA.t[Is].i] * h[TGA.t[Is].j],
                          t[TGA.t[Is].k])), ...);
}
// two-channel wgv load via float2 (c even)
template <size_t... Ps>
__device__ __forceinline__ void load_wgv2(std::index_sequence<Ps...>,
    float* __restrict__ w0, float* __restrict__ w1,
    const float* __restrict__ wg, int c) {
  float2 tmp;
  (((tmp = *reinterpret_cast<const float2*>(
        &wg[(size_t)(((int)PATHS_ARR[Ps].l1 * 4 + (int)PATHS_ARR[Ps].l2) * 4
                     + (int)PATHS_ARR[Ps].l3) * CHID + c]),
     w0[Ps] = tmp.x, w1[Ps] = tmp.y)), ...);
}

// ---------------------------------------------------------------------------
// prep_kernel: blocks [0,2048) layernorm; blocks [2048,3200) weight transpose.
// ---------------------------------------------------------------------------
__global__ __launch_bounds__(256) void prep_kernel(
    const float* __restrict__ x, const float* __restrict__ nw,
    const float* __restrict__ nb, u16* __restrict__ xnb,
    const float* __restrict__ w1, const float* __restrict__ w2,
    u16* __restrict__ w1t, u16* __restrict__ w2t) {
  int bid = blockIdx.x, tid = threadIdx.x;
  if (bid >= NNODES) {
    __shared__ float tile[32][33];
    int b2 = bid - NNODES;
    int z = b2 / 144, rem = b2 % 144;
    int by = rem / 12, bx = rem % 12;
    int R = z < 4 ? 384 : 256, C = z < 4 ? 256 : 384;
    int r0 = by * 32, c0 = bx * 32;
    if (r0 >= R || c0 >= C) return;
    const float* s = (z < 4 ? w1 : w2) + (size_t)(z & 3) * R * C;
    u16* d = (z < 4 ? w1t : w2t) + (size_t)(z & 3) * R * C;
    int tx = tid & 31, ty = tid >> 5;
    for (int rr = ty; rr < 32; rr += 8)
      tile[rr][tx] = s[(size_t)(r0 + rr) * C + (c0 + tx)];
    __syncthreads();
    for (int cc = ty; cc < 32; cc += 8)
      d[(size_t)(c0 + cc) * R + (r0 + tx)] = f2bf(tile[tx][cc]);
    return;
  }
  int n = bid;
  const float* xr = x + (size_t)n * (L2DIM * CIN);
  __shared__ float2 red[4];
  float4 v[6];
  float ssq = 0.f, m0p = 0.f;
#pragma unroll
  for (int q = 0; q < 6; ++q) {
    v[q] = reinterpret_cast<const float4*>(xr)[tid * 6 + q];
    ssq += v[q].x*v[q].x + v[q].y*v[q].y + v[q].z*v[q].z + v[q].w*v[q].w;
  }
  if (tid < 16) {
#pragma unroll
    for (int q = 0; q < 6; ++q) m0p += v[q].x + v[q].y + v[q].z + v[q].w;
  }
  float a = m0p, b = ssq;
#pragma unroll
  for (int off = 32; off > 0; off >>= 1) { a += __shfl_down(a, off, 64); b += __shfl_down(b, off, 64); }
  int lane = tid & 63, wid = tid >> 6;
  if (lane == 0) red[wid] = make_float2(a, b);
  __syncthreads();
  float sum0 = red[0].x + red[1].x + red[2].x + red[3].x;
  float ssqt = red[0].y + red[1].y + red[2].y + red[3].y;
  float mean0 = sum0 * (1.0f / CIN);
  float ss = ssqt - (float)CIN * mean0 * mean0;
  float rstd = rsqrtf(ss * (1.0f / (L2DIM * CIN)) + 1e-5f);

  int lm = tid >> 4;
  int l = LOF(lm);
  bool row0 = (lm == 0);
  int cbase = (tid & 15) * 24;
  u16* orow = xnb + (size_t)n * (L2DIM * CIN) + (size_t)tid * 24;
#pragma unroll
  for (int q = 0; q < 6; ++q) {
    int c = cbase + q * 4;
    float4 w4 = *reinterpret_cast<const float4*>(&nw[l * CIN + c]);
    float4 b4 = row0 ? *reinterpret_cast<const float4*>(&nb[c]) : make_float4(0,0,0,0);
    float sub = row0 ? mean0 : 0.f;
    float o0 = (v[q].x - sub) * rstd * w4.x + b4.x;
    float o1 = (v[q].y - sub) * rstd * w4.y + b4.y;
    float o2 = (v[q].z - sub) * rstd * w4.z + b4.z;
    float o3 = (v[q].w - sub) * rstd * w4.w + b4.w;
    ushort4 pk;
    pk.x = f2bf(o0); pk.y = f2bf(o1); pk.z = f2bf(o2); pk.w = f2bf(o3);
    *reinterpret_cast<ushort4*>(&orow[q * 4]) = pk;
  }
}

// ---------------------------------------------------------------------------
// Per-degree GEMM, swapped operands (D[chan][node-lm]), BM=128 x BN=128,
// 4 waves (2x2), wave tile 64x64, acc[4][4], 2-phase pipelined dbuf LDS.
// EXACT r11 configuration (session best, 79.8 us): z-indexed grid with
// early-return ghost blocks, NO XCD swizzle, NO nontemporal hints; resid
// prefetched in K-loop with normal cached float4 loads.
// ---------------------------------------------------------------------------
template <int KD, int NDC, bool SECOND>
__global__ __launch_bounds__(256, 2) void so3_gemm_kernel(
    const u16* __restrict__ X, const u16* __restrict__ WT,
    const float* __restrict__ bias, const float* __restrict__ resid,
    u16* __restrict__ outb, float* __restrict__ outf) {
  constexpr int KT = KD / 64;               // K-tiles (6 or 4)
  int l = blockIdx.z;
  int twol1 = 2 * l + 1;
  if ((int)blockIdx.x >= 16 * twol1) return;   // node-lm tiles per l
  int bx = blockIdx.x, by = blockIdx.y;
  int tid = threadIdx.x, lane = tid & 63, wid = tid >> 6;
  int wm = wid >> 1, wn = wid & 1;            // wm: chan half, wn: nodelm half

  __shared__ u16 Wsm[2][128 * 64];            // 2 x 16 KB (chan rows)
  __shared__ u16 Xsm[2][128 * 64];            // 2 x 16 KB (node-lm rows)

  const u16* wsrc[4];
  const u16* xsrc[4];
#pragma unroll
  for (int i = 0; i < 4; ++i) {
    int r = i * 32 + (tid >> 3);
    wsrc[i] = WT + (size_t)(l * NDC + by * 128 + r) * KD + ((tid & 7) ^ (r & 7)) * 8;
    int Rg = bx * 128 + r;
    int node = Rg / twol1;
    int lm = l * l + (Rg - node * twol1);
    xsrc[i] = X + (size_t)(node * L2DIM + lm) * KD + ((tid & 7) ^ (r & 7)) * 8;
  }

  auto stage = [&](int buf, int kt) {
#pragma unroll
    for (int i = 0; i < 4; ++i)
      __builtin_amdgcn_global_load_lds(
          (const __attribute__((address_space(1))) void*)(wsrc[i] + kt * 64),
          (__attribute__((address_space(3))) void*)(&Wsm[buf][i * 2048 + wid * 512]),
          16, 0, 0);
#pragma unroll
    for (int i = 0; i < 4; ++i)
      __builtin_amdgcn_global_load_lds(
          (const __attribute__((address_space(1))) void*)(xsrc[i] + kt * 64),
          (__attribute__((address_space(3))) void*)(&Xsm[buf][i * 2048 + wid * 512]),
          16, 0, 0);
  };

  f32x4 acc[4][4];
#pragma unroll
  for (int i = 0; i < 4; ++i)
#pragma unroll
    for (int j = 0; j < 4; ++j) acc[i][j] = (f32x4){0.f, 0.f, 0.f, 0.f};

  float4 rv[4][4];   // resid prefetch (SECOND only): rv[mf][nf]

  stage(0, 0);
  __syncthreads();
#pragma unroll
  for (int kt = 0; kt < KT; ++kt) {
    int cur = kt & 1;
    if (kt + 1 < KT) stage(cur ^ 1, kt + 1);
    if constexpr (SECOND) {
      // prefetch one mf-row of resid fragments per K-tile (KT == 4);
      // normal cached loads: partial-line reads combine in L2.
      if (kt < 4) {
        int mf = kt;
        int chan0 = by * 128 + wm * 64 + mf * 16 + (lane >> 4) * 4;
#pragma unroll
        for (int nf = 0; nf < 4; ++nf) {
          int nodelm_g = bx * 128 + wn * 64 + nf * 16 + (lane & 15);
          int node = nodelm_g / twol1;
          int lm = l * l + (nodelm_g - node * twol1);
          rv[mf][nf] = *reinterpret_cast<const float4*>(
              &resid[(size_t)(node * L2DIM + lm) * NDC + chan0]);
        }
      }
    }
#pragma unroll
    for (int ks = 0; ks < 2; ++ks) {
      short8 wf[4], xf[4];
#pragma unroll
      for (int mf = 0; mf < 4; ++mf) {
        int row = wm * 64 + mf * 16 + (lane & 15);
        int slot = (ks * 4 + (lane >> 4)) ^ (row & 7);
        wf[mf] = *reinterpret_cast<const short8*>(&Wsm[cur][row * 64 + slot * 8]);
      }
#pragma unroll
      for (int nf = 0; nf < 4; ++nf) {
        int row = wn * 64 + nf * 16 + (lane & 15);
        int slot = (ks * 4 + (lane >> 4)) ^ (row & 7);
        xf[nf] = *reinterpret_cast<const short8*>(&Xsm[cur][row * 64 + slot * 8]);
      }
#pragma unroll
      for (int mf = 0; mf < 4; ++mf)
#pragma unroll
        for (int nf = 0; nf < 4; ++nf)
          acc[mf][nf] = __builtin_amdgcn_mfma_f32_16x16x32_bf16(wf[mf], xf[nf], acc[mf][nf], 0, 0, 0);
    }
    __syncthreads();
  }

  // ---- epilogue: lane holds 4 consecutive chans of one node-lm row ----
#pragma unroll
  for (int mf = 0; mf < 4; ++mf) {
#pragma unroll
    for (int nf = 0; nf < 4; ++nf) {
      int nodelm_g = bx * 128 + wn * 64 + nf * 16 + (lane & 15);
      int node = nodelm_g / twol1;
      int lm = l * l + (nodelm_g - node * twol1);
      int chan0 = by * 128 + wm * 64 + mf * 16 + (lane >> 4) * 4;
      size_t base = (size_t)(node * L2DIM + lm) * NDC + chan0;
      float4 v = make_float4(acc[mf][nf][0], acc[mf][nf][1],
                             acc[mf][nf][2], acc[mf][nf][3]);
      if (l == 0) {
        float4 b4 = *reinterpret_cast<const float4*>(&bias[chan0]);
        v.x += b4.x; v.y += b4.y; v.z += b4.z; v.w += b4.w;
      }
      if (!SECOND) {
        ushort4 pk;
        pk.x = f2bf(v.x); pk.y = f2bf(v.y); pk.z = f2bf(v.z); pk.w = f2bf(v.w);
        *reinterpret_cast<ushort4*>(&outb[base]) = pk;
      } else {
        v.x += rv[mf][nf].x; v.y += rv[mf][nf].y;
        v.z += rv[mf][nf].z; v.w += rv[mf][nf].w;
        *reinterpret_cast<float4*>(&outf[base]) = v;
      }
    }
  }
}

// ---------------------------------------------------------------------------
// Depthwise Gaunt TP, 2 channels/thread (u32 packed I/O), block covers 2 nodes.
// ---------------------------------------------------------------------------
__global__ __launch_bounds__(256) void gaunt_kernel(
    const u16* __restrict__ hb, const float* __restrict__ wg,
    u16* __restrict__ tb) {
  int tid = threadIdx.x;
  int n = blockIdx.x * 2 + (tid >> 7);
  int c = (tid & 127) * 2;
  const u16* hr = hb + (size_t)n * (L2DIM * CHID) + c;
  float h0[16], h1[16];
#pragma unroll
  for (int i = 0; i < 16; ++i) {
    u32 w = *reinterpret_cast<const u32*>(&hr[i * CHID]);
    h0[i] = bf2f((u16)(w & 0xffffu));
    h1[i] = bf2f((u16)(w >> 16));
  }

  float w0[NPATHS], w1[NPATHS];
  load_wgv2(std::make_index_sequence<NPATHS>{}, w0, w1, wg, c);

  float t0[16], t1[16];
#pragma unroll
  for (int k = 0; k < 16; ++k) { t0[k] = 0.f; t1[k] = 0.f; }

  gaunt_terms(std::make_index_sequence<NNZ>{}, t0, h0, w0);
  gaunt_terms(std::make_index_sequence<NNZ>{}, t1, h1, w1);

  u16* tr = tb + (size_t)n * (L2DIM * CHID) + c;
#pragma unroll
  for (int k = 0; k < 16; ++k) {
    u32 o = (u32)f2bf(t0[k]) | ((u32)f2bf(t1[k]) << 16);
    *reinterpret_cast<u32*>(&tr[k * CHID]) = o;
  }
}

// ---------------------------------------------------------------------------
extern "C" void kernel_launch(void* const* d_in, const int* in_sizes, int n_in,
                              void* d_out, int out_size, void* d_ws, size_t ws_size,
                              hipStream_t stream) {
  const float* inputs = (const float*)d_in[0];
  // d_in[1] = batch (unused: drop paths disabled)
  const float* norm_w = (const float*)d_in[2];
  const float* norm_b = (const float*)d_in[3];
  const float* w1     = (const float*)d_in[4];
  const float* b1     = (const float*)d_in[5];
  const float* wga    = (const float*)d_in[6];
  const float* w2     = (const float*)d_in[7];
  const float* b2     = (const float*)d_in[8];
  float* out = (float*)d_out;

  uint8_t* ws = (uint8_t*)d_ws;
  u16*   w1t = (u16*)(ws + 16384);          // [4][256][384] bf16, 768 KB
  u16*   w2t = (u16*)(ws + 802816);         // [4][384][256] bf16, 768 KB
  u16*   xnb = (u16*)(ws + 1589248);        // [2048][16][384] bf16, 24 MB
  u16*   tb  = xnb;                         // reuse after GEMM1 consumed xnb
  u16*   hb  = (u16*)(ws + 26755072);       // [2048][16][256] bf16, 16 MB

  prep_kernel<<<NNODES + 1152, 256, 0, stream>>>(
      inputs, norm_w, norm_b, xnb, w1, w2, w1t, w2t);
  // gemm1: X=xnb (K=384), W=w1t (256 chans -> by 0..1) -> hb bf16
  so3_gemm_kernel<CIN, CHID, false><<<dim3(112, 2, 4), 256, 0, stream>>>(
      xnb, w1t, b1, nullptr, hb, nullptr);
  gaunt_kernel<<<NNODES / 2, 256, 0, stream>>>(hb, wga, tb);
  // gemm2: X=tb (K=256), W=w2t (384 chans -> by 0..2) -> out f32 (+resid)
  so3_gemm_kernel<CHID, CIN, true><<<dim3(112, 3, 4), 256, 0, stream>>>(
      tb, w2t, b2, inputs, nullptr, out);
}